// Round 22
// baseline (423.064 us; speedup 1.0000x reference)
//
#include <hip/hip_runtime.h>
#include <hip/hip_bf16.h>
#include <stdint.h>

typedef unsigned short u16;
typedef short bf16x8 __attribute__((ext_vector_type(8)));
typedef short s16x4 __attribute__((ext_vector_type(4)));
typedef float f32x4 __attribute__((ext_vector_type(4)));

#define DEV static __device__ __forceinline__

DEV float b2f(u16 u) { return __uint_as_float(((unsigned)u) << 16); }
DEV u16 f2bu(float x) {
  union { __hip_bfloat16 h; u16 u; } c;
  c.h = __float2bfloat16(x);
  return c.u;
}

DEV void gload16(const void* g, void* l) {
  __builtin_amdgcn_global_load_lds(
      (const __attribute__((address_space(1))) void*)(uintptr_t)g,
      (__attribute__((address_space(3))) void*)(uintptr_t)l, 16, 0, 0);
}

struct Epi {
  const float* bias;
  const float* alpha_ptr;
  const u16* add;
  long ld_add, add_bs;
  int relu;
  u16* outb; long ldo;  long outb_bs;
  int padrow;
  u16* outt; long ldot; long outt_bs;
  int padmap;
  float* outf; long ldof; long outf_bs;
  float* outu;
  int mode;  // 1=fused router; 2=attnV bounce->pad; 3=conv1 (outp f32 unpad + vcT bounce)
  u16 *f_qT, *f_pc, *f_pcT, *f_vp, *f_rpT, *f_qc, *f_rc;
};

// ============ ring-pipelined 128xBN GEMM: D[M][N] = A[M][K] * Bt[N][K]^T ============
// 3-slot LDS ring + counted vmcnt; one raw s_barrier/K-step; vmcnt never 0 until last.
// XOR-swizzled LDS (0 conflicts), bijective XCD chunking GROUP=8 (proven; 32 regressed),
// TPB=512: 8 waves (R13/R14). All epilogues LDS-bounced for 16B stores.
// Converged config (R17/R20/R21): RING 4 null, GROUP 32 worse, split-K worse, setprio null.
template <int BN, int TPB>
__global__ __launch_bounds__(TPB) void gemm_bt(
    const u16* __restrict__ A, long lda, long a_bs,
    const u16* __restrict__ Bt, long ldb, long b_bs,
    int K, int conv9, int zdiv, Epi e)
{
  constexpr int WAVES = TPB / 64;
  constexpr int NW_N = (WAVES == 8) ? 4 : 2;
  constexpr int WCOLS = BN / NW_N;
  constexpr int FNW = WCOLS / 16;
  constexpr int AG = 512 / TPB;
  constexpr int BG = (BN * 4) / TPB;
  constexpr int LPS = AG + BG;
  constexpr int SLOT = 4096 + BN * 32;
  __shared__ u16 SMEM[3 * SLOT];

  const int bz = blockIdx.z;
  int batch = bz, ksteps = K >> 5, ksbase = 0;
  if (zdiv > 1) {
    batch = bz / zdiv;
    int sl = bz - batch * zdiv;
    ksteps = (K / zdiv) >> 5;
    ksbase = sl * ksteps;
  }
  const int gx = gridDim.x, gy = gridDim.y;
  const int nwg = gx * gy;
  const int orig = blockIdx.y * gx + blockIdx.x;
  const int q8 = nwg >> 3, r8 = nwg & 7;
  const int xcd = orig & 7, lid = orig >> 3;
  const int wgid = (xcd < r8 ? xcd * (q8 + 1) : r8 * (q8 + 1) + (xcd - r8) * q8) + lid;
  const int GROUP = 8;
  const int span = GROUP * gy;
  const int group_id = wgid / span;
  const int first_m = group_id * GROUP;
  const int gsz = (GROUP < gx - first_m) ? GROUP : (gx - first_m);
  const int rem = wgid - group_id * span;
  const int bm = first_m + rem % gsz;
  const int bn = rem / gsz;

  const u16* Ab = A + (long)batch * a_bs;
  const u16* Bb = Bt + (long)batch * b_bs;
  const int m0 = bm * 128;
  const int n0 = bn * BN;
  const int t = threadIdx.x;
  const int w = t >> 6, l = t & 63;
  const int wr = w / NW_N, wc = w % NW_N;
  const int lr = l & 15, lg = l >> 4;

  f32x4 acc[4][FNW];
#pragma unroll
  for (int i = 0; i < 4; ++i)
#pragma unroll
    for (int j = 0; j < FNW; ++j) acc[i][j] = (f32x4){0.f, 0.f, 0.f, 0.f};

  auto stage = [&](int ks, int slot) {
    u16* As = SMEM + slot * SLOT;
    u16* Bs = As + 4096;
    const int k0 = ks << 5;
    long brow = 0;
    int bk0 = k0;
    if (conv9) {
      int s = k0 >> 9;
      int kh = s / 3, kw = s - kh * 3;
      brow = (long)((kh - 1) * 66 + (kw - 1));
      bk0 = k0 & 511;
    }
#pragma unroll
    for (int r = 0; r < AG; ++r) {
      int idx = r * TPB + t;
      int row = idx >> 2;
      int ko = (((idx & 3) ^ ((row >> 1) & 3)) << 3);
      gload16(Ab + (long)(m0 + row) * lda + (k0 + ko),
              (char*)As + ((r * TPB + (t & (TPB - 64))) << 4));
    }
#pragma unroll
    for (int r = 0; r < BG; ++r) {
      int idx = r * TPB + t;
      int row = idx >> 2;
      int ko = (((idx & 3) ^ ((row >> 1) & 3)) << 3);
      gload16(Bb + ((long)(n0 + row) + brow) * ldb + (bk0 + ko),
              (char*)Bs + ((r * TPB + (t & (TPB - 64))) << 4));
    }
  };

  auto compute = [&](int slot) {
    const u16* As = SMEM + slot * SLOT;
    const u16* Bs = As + 4096;
    __builtin_amdgcn_s_setprio(1);
    bf16x8 af[4], bfr[FNW];
#pragma unroll
    for (int i = 0; i < 4; ++i) {
      int row = wr * 64 + i * 16 + lr;
      int cg = lg ^ ((row >> 1) & 3);
      af[i] = *(const bf16x8*)(As + row * 32 + cg * 8);
    }
#pragma unroll
    for (int j = 0; j < FNW; ++j) {
      int row = wc * WCOLS + j * 16 + lr;
      int cg = lg ^ ((row >> 1) & 3);
      bfr[j] = *(const bf16x8*)(Bs + row * 32 + cg * 8);
    }
#pragma unroll
    for (int i = 0; i < 4; ++i)
#pragma unroll
      for (int j = 0; j < FNW; ++j)
        acc[i][j] = __builtin_amdgcn_mfma_f32_16x16x32_bf16(af[i], bfr[j], acc[i][j], 0, 0, 0);
    __builtin_amdgcn_s_setprio(0);
  };

  const int nk = ksteps;
  stage(ksbase, 0);
  if (nk > 1) stage(ksbase + 1, 1);
  for (int tt = 0; tt < nk; ++tt) {
    if (tt < nk - 1) {
      if constexpr (LPS == 4) asm volatile("s_waitcnt vmcnt(4)" ::: "memory");
      else if constexpr (LPS == 3) asm volatile("s_waitcnt vmcnt(3)" ::: "memory");
      else asm volatile("s_waitcnt vmcnt(2)" ::: "memory");
    } else {
      asm volatile("s_waitcnt vmcnt(0)" ::: "memory");
    }
    __builtin_amdgcn_s_barrier();
    if (tt + 2 < nk) stage(ksbase + tt + 2, (tt + 2) % 3);
    compute(tt % 3);
    asm volatile("s_waitcnt lgkmcnt(0)" ::: "memory");
  }

  const float alpha = e.alpha_ptr ? e.alpha_ptr[0] : 1.0f;

  if (e.mode == 1) {
    const int seg = (m0 < 128) ? 0 : (m0 < 640) ? 1 : (m0 < 1152) ? 2 :
                    (m0 < 1664) ? 3 : (m0 < 2176) ? 4 : 5;
    const bool doT = (seg == 0 || seg == 1 || seg == 3);
    const bool doR = (seg == 1 || seg == 2 || seg == 4 || seg == 5);
    const bool doRelu = (seg == 1 || seg == 3 || seg == 5);

    if (doT) {
      __syncthreads();
#pragma unroll
      for (int i = 0; i < 4; ++i) {
#pragma unroll
        for (int j = 0; j < FNW; ++j) {
          const int gnl = wc * WCOLS + j * 16 + lr;
#pragma unroll
          for (int q = 0; q < 4; ++q) {
            const int gml = wr * 64 + i * 16 + lg * 4 + q;
            float v = acc[i][j][q] + e.bias[m0 + gml];
            if (doRelu) v = fmaxf(v, 0.f);
            SMEM[gnl * 128 + (((gml >> 3) ^ (gnl & 7)) << 3) + (gml & 7)] = f2bu(v);
          }
        }
      }
      __syncthreads();
      u16* dst; long ld;
      if (seg == 0)      { dst = e.f_qT  + ((long)batch * 4096 + n0) * 128;                ld = 128; }
      else if (seg == 1) { dst = e.f_pcT + ((long)batch * 4096 + n0) * 512 + (m0 - 128);   ld = 512; }
      else               { dst = e.f_rpT + ((long)batch * 4096 + n0) * 512 + (m0 - 1152);  ld = 512; }
#pragma unroll
      for (int k = 0; k < (BN * 16) / TPB; ++k) {
        int chunk = k * TPB + t;
        int row = chunk >> 4, c16 = chunk & 15;
        bf16x8 vv = *(const bf16x8*)(SMEM + row * 128 + ((c16 ^ (row & 7)) << 3));
        *(bf16x8*)(dst + (long)row * ld + c16 * 8) = vv;
      }
    }
    if (doR) {
      __syncthreads();
#pragma unroll
      for (int i = 0; i < 4; ++i) {
#pragma unroll
        for (int j = 0; j < FNW; ++j) {
          const int gnl = wc * WCOLS + j * 16 + lr;
#pragma unroll
          for (int q = 0; q < 4; ++q) {
            const int gml = wr * 64 + i * 16 + lg * 4 + q;
            float v = acc[i][j][q] + e.bias[m0 + gml];
            if (doRelu) v = fmaxf(v, 0.f);
            SMEM[gml * 128 + (((gnl >> 3) ^ (gml & 7)) << 3) + (gnl & 7)] = f2bu(v);
          }
        }
      }
      __syncthreads();
      const int mb = (seg == 1) ? 128 : (seg == 2) ? 640 : (seg == 4) ? 1664 : 2176;
      u16* rbase = (seg == 1) ? e.f_pc : (seg == 2) ? e.f_vp : (seg == 4) ? e.f_qc : e.f_rc;
      u16* rdst = rbase + ((long)batch * 512 + (m0 - mb)) * 4096 + n0;
#pragma unroll
      for (int k = 0; k < (BN * 16) / TPB; ++k) {
        int chunk = k * TPB + t;
        int row = chunk >> 4, c16 = chunk & 15;
        bf16x8 vv = *(const bf16x8*)(SMEM + row * 128 + ((c16 ^ (row & 7)) << 3));
        *(bf16x8*)(rdst + (long)row * 4096 + c16 * 8) = vv;
      }
    }
    return;
  }

  if (e.mode == 2) {
    __syncthreads();
#pragma unroll
    for (int i = 0; i < 4; ++i) {
#pragma unroll
      for (int j = 0; j < FNW; ++j) {
        const int gn = n0 + wc * WCOLS + j * 16 + lr;
#pragma unroll
        for (int q = 0; q < 4; ++q) {
          const int gm = m0 + wr * 64 + i * 16 + lg * 4 + q;
          float v = acc[i][j][q] * alpha +
                    b2f(e.add[(long)batch * e.add_bs + (long)gm * e.ld_add + gn]);
          const int gnl = gn - n0, gml = gm - m0;
          SMEM[gnl * 128 + (((gml >> 3) ^ (gnl & 7)) << 3) + (gml & 7)] = f2bu(v);
        }
      }
    }
    __syncthreads();
#pragma unroll
    for (int k = 0; k < (BN * 16) / TPB; ++k) {
      int chunk = k * TPB + t;
      int row = chunk >> 4, c16 = chunk & 15;
      int gnr = n0 + row;
      long rowo = (long)((gnr >> 6) + 1) * 66 + (gnr & 63) + 1;
      bf16x8 vv = *(const bf16x8*)(SMEM + row * 128 + ((c16 ^ (row & 7)) << 3));
      *(bf16x8*)(e.outt + (long)batch * e.outt_bs + rowo * e.ldot + m0 + c16 * 8) = vv;
    }
    return;
  }

  if (e.mode == 3) {
    __syncthreads();
#pragma unroll
    for (int i = 0; i < 4; ++i) {
#pragma unroll
      for (int j = 0; j < FNW; ++j) {
        const int gn = n0 + wc * WCOLS + j * 16 + lr;
#pragma unroll
        for (int q = 0; q < 4; ++q) {
          const int gm = m0 + wr * 64 + i * 16 + lg * 4 + q;
          float v = fmaxf(acc[i][j][q] + e.bias[gm], 0.f);
          int ph = gn / 66, pw = gn - ph * 66;
          if (ph >= 1 && ph <= 64 && pw >= 1 && pw <= 64)
            e.outu[(long)batch * 2097152 + (long)gm * 4096 + (ph - 1) * 64 + (pw - 1)] = v;
          const int gnl = gn - n0, gml = gm - m0;
          SMEM[gnl * 128 + (((gml >> 3) ^ (gnl & 7)) << 3) + (gml & 7)] = f2bu(v);
        }
      }
    }
    __syncthreads();
#pragma unroll
    for (int k = 0; k < (BN * 16) / TPB; ++k) {
      int chunk = k * TPB + t;
      int row = chunk >> 4, c16 = chunk & 15;
      int gnr = n0 + row;
      int ph = gnr / 66, pw = gnr - ph * 66;
      if (ph >= 1 && ph <= 64 && pw >= 1 && pw <= 64) {
        long nn = (long)(ph - 1) * 64 + (pw - 1);
        bf16x8 vv = *(const bf16x8*)(SMEM + row * 128 + ((c16 ^ (row & 7)) << 3));
        *(bf16x8*)(e.outt + ((long)batch * 4096 + nn) * 512 + m0 + c16 * 8) = vv;
      }
    }
    return;
  }

#pragma unroll
  for (int i = 0; i < 4; ++i) {
#pragma unroll
    for (int j = 0; j < FNW; ++j) {
      const int gn = n0 + wc * WCOLS + j * 16 + lr;
#pragma unroll
      for (int q = 0; q < 4; ++q) {
        const int gm = m0 + wr * 64 + i * 16 + lg * 4 + q;
        float v = acc[i][j][q] * alpha;
        if (e.bias) v += e.bias[gm];
        if (e.add) v += b2f(e.add[(long)batch * e.add_bs + (long)gm * e.ld_add + gn]);
        if (e.relu) v = fmaxf(v, 0.f);
        if (e.outb) {
          long rowo = gm;
          if (e.padrow) rowo = (long)((gm >> 6) + 1) * 66 + (gm & 63) + 1;
          e.outb[(long)batch * e.outb_bs + rowo * e.ldo + gn] = f2bu(v);
        }
        if (e.outf)
          e.outf[(long)bz * e.outf_bs + (long)gm * e.ldof + gn] = v;
        if (e.outu) {
          int ph = gn / 66, pw = gn - ph * 66;
          if (ph >= 1 && ph <= 64 && pw >= 1 && pw <= 64)
            e.outu[(long)batch * 2097152 + (long)gm * 4096 + (ph - 1) * 64 + (pw - 1)] = v;
        }
        if (e.outt) {
          long rt = gn;
          if (e.padmap) rt = (long)((gn >> 6) + 1) * 66 + (gn & 63) + 1;
          e.outt[(long)batch * e.outt_bs + rt * e.ldot + gm] = f2bu(v);
        }
      }
    }
  }
}

// ---------------- flash attention (position branch), bf16 O-partials ----------------
__global__ __launch_bounds__(512, 2) void k_flash(
    const u16* __restrict__ qT, const u16* __restrict__ kT,
    const u16* __restrict__ vp,
    u16* __restrict__ opart, float* __restrict__ lpart)
{
  __shared__ u16 kt_lds[2][64 * 128];
  __shared__ u16 p_lds[128 * 64];

  const int orig = blockIdx.x;
  const int xcd = orig & 7;
  const int qtile = orig >> 3;
  const int split = xcd & 3;
  const int b = xcd >> 2;

  const int t = threadIdx.x;
  const int w = t >> 6;
  const int l = t & 63;
  const int lr = l & 15, lg = l >> 4;
  const int n0 = qtile * 128;
  const int m_base = split * 1024;

  const u16* qb = qT + ((long)b * 4096 + n0 + w * 16) * 128;
  const u16* kb = kT + ((long)b * 4096 + m_base) * 128;

  bf16x8 qf[4];
#pragma unroll
  for (int ks = 0; ks < 4; ++ks)
    qf[ks] = *(const bf16x8*)(qb + (long)lr * 128 + ks * 32 + lg * 8);

  f32x4 acc[8][4];
#pragma unroll
  for (int i = 0; i < 8; ++i)
#pragma unroll
    for (int j = 0; j < 4; ++j) acc[i][j] = (f32x4){0.f, 0.f, 0.f, 0.f};
  float lrun[4] = {0.f, 0.f, 0.f, 0.f};

  auto stage = [&](int mt, int buf) {
#pragma unroll
    for (int r = 0; r < 2; ++r) {
      int idx = (r << 9) + t;
      int row = idx >> 4;
      int g = idx & 15;
      int gs = g ^ (row & 7);
      gload16(kb + ((long)(mt * 64 + row)) * 128 + gs * 8,
              (char*)(&kt_lds[buf][0]) + (((r << 9) + (t & 448)) << 4));
    }
  };

  stage(0, 0);
  __syncthreads();

  const int nt = 16;
  for (int mt = 0; mt < nt; ++mt) {
    const int cur = mt & 1;
    if (mt + 1 < nt) stage(mt + 1, cur ^ 1);

    bf16x8 vv[4][2];
#pragma unroll
    for (int cs = 0; cs < 4; ++cs) {
#pragma unroll
      for (int k2 = 0; k2 < 2; ++k2) {
        const u16* va = vp + ((long)b * 512 + w * 64 + cs * 16 + lr) * 4096 +
                        m_base + mt * 64 + k2 * 32 + lg * 8;
        vv[cs][k2] = *(const bf16x8*)va;
      }
    }

    f32x4 sacc[4];
#pragma unroll
    for (int ms = 0; ms < 4; ++ms) sacc[ms] = (f32x4){0.f, 0.f, 0.f, 0.f};
#pragma unroll
    for (int ms = 0; ms < 4; ++ms) {
#pragma unroll
      for (int ks = 0; ks < 4; ++ks) {
        int row = ms * 16 + lr;
        int gs = (ks * 4 + lg) ^ (row & 7);
        bf16x8 kf = *(const bf16x8*)(&kt_lds[cur][0] + row * 128 + gs * 8);
        sacc[ms] = __builtin_amdgcn_mfma_f32_16x16x32_bf16(qf[ks], kf, sacc[ms], 0, 0, 0);
      }
    }

    float rs[4] = {0.f, 0.f, 0.f, 0.f};
#pragma unroll
    for (int ms = 0; ms < 4; ++ms) {
#pragma unroll
      for (int q = 0; q < 4; ++q) {
        float p = __expf(sacc[ms][q]);
        rs[q] += p;
        int prow = w * 16 + 4 * lg + q;
        int m = ms * 16 + lr;
        int gm = m >> 3, offm = m & 7;
        int gsm = gm ^ (prow & 7);
        p_lds[prow * 64 + gsm * 8 + offm] = f2bu(p);
      }
    }
#pragma unroll
    for (int q = 0; q < 4; ++q) {
      rs[q] += __shfl_xor(rs[q], 1);
      rs[q] += __shfl_xor(rs[q], 2);
      rs[q] += __shfl_xor(rs[q], 4);
      rs[q] += __shfl_xor(rs[q], 8);
      lrun[q] += rs[q];
    }

    __syncthreads();

    __builtin_amdgcn_s_setprio(1);
#pragma unroll
    for (int ntl = 0; ntl < 8; ++ntl) {
      int row = ntl * 16 + lr;
      int gs0 = (0 * 4 + lg) ^ (row & 7);
      int gs1 = (1 * 4 + lg) ^ (row & 7);
      bf16x8 pf0 = *(const bf16x8*)(&p_lds[0] + row * 64 + gs0 * 8);
      bf16x8 pf1 = *(const bf16x8*)(&p_lds[0] + row * 64 + gs1 * 8);
#pragma unroll
      for (int cs = 0; cs < 4; ++cs) {
        acc[ntl][cs] = __builtin_amdgcn_mfma_f32_16x16x32_bf16(pf0, vv[cs][0], acc[ntl][cs], 0, 0, 0);
        acc[ntl][cs] = __builtin_amdgcn_mfma_f32_16x16x32_bf16(pf1, vv[cs][1], acc[ntl][cs], 0, 0, 0);
      }
    }
    __builtin_amdgcn_s_setprio(0);
    __syncthreads();
  }

  const long pbase = ((long)split * 2 + b) * 4096;
  if (lr == 0) {
#pragma unroll
    for (int q = 0; q < 4; ++q)
      lpart[pbase + n0 + w * 16 + 4 * lg + q] = lrun[q];
  }
#pragma unroll
  for (int ntl = 0; ntl < 8; ++ntl) {
#pragma unroll
    for (int cs = 0; cs < 4; ++cs) {
#pragma unroll
      for (int q = 0; q < 4; ++q) {
        long row = n0 + ntl * 16 + 4 * lg + q;
        int col = w * 64 + cs * 16 + lr;
        opart[(pbase + row) * 512 + col] = f2bu(acc[ntl][cs][q]);
      }
    }
  }
}

__global__ __launch_bounds__(256) void k_combine_p(
    const u16* __restrict__ opart, const float* __restrict__ lpart,
    const u16* __restrict__ rpT, const float* __restrict__ gamma_p,
    u16* __restrict__ padi)
{
  const int t = threadIdx.x;
  const long rg = (long)blockIdx.x * 4 + (t >> 6);
  const int b = (int)(rg >> 12), n = (int)(rg & 4095);
  const int l = t & 63;
  const int c0 = l * 8;
  float lsum = 0.f;
#pragma unroll
  for (int s = 0; s < 4; ++s) lsum += lpart[((long)s * 2 + b) * 4096 + n];
  float o[8];
#pragma unroll
  for (int i = 0; i < 8; ++i) o[i] = 0.f;
#pragma unroll
  for (int s = 0; s < 4; ++s) {
    const u16* op = opart + ((((long)s * 2 + b) * 4096 + n) * 512) + c0;
    bf16x8 a = *(const bf16x8*)op;
#pragma unroll
    for (int i = 0; i < 8; ++i) o[i] += b2f((u16)a[i]);
  }
  const float g = gamma_p[0];
  const float inv = 1.0f / lsum;
  bf16x8 rv = *(const bf16x8*)(rpT + ((long)b * 4096 + n) * 512 + c0);
  bf16x8 outv;
#pragma unroll
  for (int i = 0; i < 8; ++i)
    outv[i] = (short)f2bu(g * o[i] * inv + b2f((u16)rv[i]));
  const int h = n >> 6, ww = n & 63;
  *(bf16x8*)(padi + ((long)b * 4736 + (long)(h + 1) * 66 + ww + 1) * 512 + c0) = outv;
}

// ---- merged prologue: blocks [0,4096) transpose x; blocks [4096,6144) weight prep ----
__global__ __launch_bounds__(256) void k_pre(
    const float* __restrict__ x, u16* __restrict__ xt,
    const float* wq_p, const float* wpc, const float* spc,
    const float* wv, const float* wrp, const float* srp,
    const float* wq_c, const float* wrc, const float* src_,
    const float* wk, const float* wpf, const float* spf,
    const float* wcf, const float* scf,
    const float* bq_p, const float* bpc, const float* tpc,
    const float* bv, const float* brp, const float* trp,
    const float* bq_c, const float* brc, const float* trc,
    const float* bpf, const float* tpf,
    const float* bcf, const float* tcf,
    u16* wall, u16* wpfb, u16* wcfb, u16* wkb,
    float* biasAll, float* biasPF, float* biasCF)
{
  const int bid = blockIdx.x;
  const int t = threadIdx.x;

  if (bid < 4096) {
    __shared__ float tile[64][65];
    const int b = bid >> 11;
    const int remb = bid & 2047;
    const int c0 = (remb & 31) * 64;
    const int n0 = (remb >> 5) * 64;
    const int tn = t & 63, tc = t >> 6;
    const float* xp = x + ((long)b * 2048 + c0) * 4096 + n0;
#pragma unroll
    for (int i = 0; i < 16; ++i)
      tile[tc + i * 4][tn] = xp[(long)(tc + i * 4) * 4096 + tn];
    __syncthreads();
    u16* xo = xt + ((long)b * 4096 + n0) * 2048 + c0;
#pragma unroll
    for (int i = 0; i < 2; ++i) {
      int chunk = i * 256 + t;
      int n = chunk >> 3, c8 = chunk & 7;
      bf16x8 o;
#pragma unroll
      for (int j = 0; j < 8; ++j) o[j] = (short)f2bu(tile[c8 * 8 + j][n]);
      *(bf16x8*)(xo + (long)n * 2048 + c8 * 8) = o;
    }
    return;
  }

  // ---- weight/bias prep, grid-stride over 2048 blocks (full standalone parallelism) ----
  const long W4 = (2688L * 2048) / 4;
  const long W3 = 512L * 512 * 9;
  const long TOT = W4 + 2 * W3 + 65536 + 3712;
  for (long i = (long)(bid - 4096) * 256 + t; i < TOT; i += 2048L * 256) {
    if (i < W4) {
      long i4 = i << 2;
      int r = (int)(i4 >> 11), c = (int)(i4 & 2047);
      const float* base; float s = 1.f;
      if (r < 128)       { base = wq_p + (long)r * 2048; }
      else if (r < 640)  { int rr = r - 128;  base = wpc + (long)rr * 2048; s = spc[rr]; }
      else if (r < 1152) { int rr = r - 640;  base = wv  + (long)rr * 2048; }
      else if (r < 1664) { int rr = r - 1152; base = wrp + (long)rr * 2048; s = srp[rr]; }
      else if (r < 2176) { int rr = r - 1664; base = wq_c + (long)rr * 2048; }
      else               { int rr = r - 2176; base = wrc + (long)rr * 2048; s = src_[rr]; }
      f32x4 v = *(const f32x4*)(base + c);
      s16x4 o;
#pragma unroll
      for (int j = 0; j < 4; ++j) o[j] = (short)f2bu(s * v[j]);
      *(s16x4*)(wall + i4) = o;
    } else if (i < W4 + 2 * W3) {
      int which = (i < W4 + W3) ? 0 : 1;
      long j = i - W4 - (long)which * W3;
      int o = (int)(j / (512 * 9));
      long rem = j - (long)o * (512 * 9);
      int khw = (int)(rem >> 9);
      int c = (int)(rem & 511);
      int kh = khw / 3, kw = khw - kh * 3;
      const float* wsrc = which ? wcf : wpf;
      const float* ssrc = which ? scf : spf;
      u16* dst = which ? wcfb : wpfb;
      dst[j] = f2bu(ssrc[o] * wsrc[(((long)o * 512 + c) * 3 + kh) * 3 + kw]);
    } else if (i < W4 + 2 * W3 + 65536) {
      long j = i - W4 - 2 * W3;
      wkb[j] = f2bu(wk[j]);
    } else {
      long j = i - W4 - 2 * W3 - 65536;
      if (j < 2688) {
        int r = (int)j;
        float v;
        if (r < 128) v = bq_p[r];
        else if (r < 640)  { int k = r - 128;  v = spc[k] * bpc[k] + tpc[k]; }
        else if (r < 1152) { int k = r - 640;  v = bv[k]; }
        else if (r < 1664) { int k = r - 1152; v = srp[k] * brp[k] + trp[k]; }
        else if (r < 2176) { int k = r - 1664; v = bq_c[k]; }
        else               { int k = r - 2176; v = src_[k] * brc[k] + trc[k]; }
        biasAll[r] = v;
      } else if (j < 3200) {
        int k = (int)(j - 2688);
        biasPF[k] = spf[k] * bpf[k] + tpf[k];
      } else {
        int k = (int)(j - 3200);
        biasCF[k] = scf[k] * bcf[k] + tcf[k];
      }
    }
  }
}

// ---- channel softmax summing 4 split-K slices ----
__global__ void k_softmax_chan(const float* __restrict__ EP, u16* __restrict__ A) {
  const long row = blockIdx.x;
  const int batch = (int)(row >> 9), r = (int)(row & 511);
  const int l = threadIdx.x;
  float v[8];
#pragma unroll
  for (int i = 0; i < 8; ++i) v[i] = 0.f;
  for (int s = 0; s < 4; ++s) {
    const float* e = EP + (((long)batch * 4 + s) * 512 + r) * 512 + l * 8;
#pragma unroll
    for (int i = 0; i < 8; ++i) v[i] += e[i];
  }
  float mn = 1e30f;
#pragma unroll
  for (int i = 0; i < 8; ++i) mn = fminf(mn, v[i]);
  for (int o = 32; o > 0; o >>= 1) mn = fminf(mn, __shfl_xor(mn, o));
  float s = 0.f;
#pragma unroll
  for (int i = 0; i < 8; ++i) { v[i] = __expf(mn - v[i]); s += v[i]; }
  for (int o = 32; o > 0; o >>= 1) s += __shfl_xor(s, o);
  const float inv = 1.0f / s;
  u16* out = A + row * 512;
#pragma unroll
  for (int i = 0; i < 8; ++i) out[l * 8 + i] = f2bu(v[i] * inv);
}

// =======================================================================================
extern "C" void kernel_launch(void* const* d_in, const int* in_sizes, int n_in,
                              void* d_out, int out_size, void* d_ws, size_t ws_size,
                              hipStream_t stream) {
  (void)in_sizes; (void)n_in; (void)out_size;
  const float* x     = (const float*)d_in[0];
  const float* wq_p  = (const float*)d_in[1];
  const float* bq_p  = (const float*)d_in[2];
  const float* wpc   = (const float*)d_in[3];
  const float* bpc   = (const float*)d_in[4];
  const float* spc   = (const float*)d_in[5];
  const float* tpc   = (const float*)d_in[6];
  const float* wk    = (const float*)d_in[7];
  const float* wv    = (const float*)d_in[9];
  const float* bv    = (const float*)d_in[10];
  const float* wrp   = (const float*)d_in[11];
  const float* brp   = (const float*)d_in[12];
  const float* srp   = (const float*)d_in[13];
  const float* trp   = (const float*)d_in[14];
  const float* wpf   = (const float*)d_in[15];
  const float* bpf   = (const float*)d_in[16];
  const float* spf   = (const float*)d_in[17];
  const float* tpf   = (const float*)d_in[18];
  const float* gamma_p = (const float*)d_in[19];
  const float* wq_c  = (const float*)d_in[20];
  const float* bq_c  = (const float*)d_in[21];
  const float* wrc   = (const float*)d_in[22];
  const float* brc   = (const float*)d_in[23];
  const float* src_  = (const float*)d_in[24];
  const float* trc   = (const float*)d_in[25];
  const float* wcf   = (const float*)d_in[26];
  const float* bcf   = (const float*)d_in[27];
  const float* scf   = (const float*)d_in[28];
  const float* tcf   = (const float*)d_in[29];
  const float* gamma_c = (const float*)d_in[30];

  float* outc = (float*)d_out;
  float* outp = outc + 4194304;

  if (ws_size < 151000000ULL) return;

  char* ws = (char*)d_ws;
  size_t off = 0;
  auto alloc = [&](size_t sz) { void* p = ws + off; off += (sz + 255) & ~(size_t)255; return p; };

  char* region0 = (char*)alloc(67108864);
  u16* xbT     = (u16*)region0;                 // [B][4096][2048]
  u16* Wall    = (u16*)(region0 + 33554432);    // [2688][2048]
  u16* wkb     = (u16*)(region0 + 44564480);    // [128][512]
  u16* opart   = (u16*)region0;                 // [4][B][4096][512] bf16 (33.5MB)
  u16* wpfb  = (u16*)alloc(4718592);
  u16* wcfb  = (u16*)alloc(4718592);
  float* biasAll = (float*)alloc(2688 * 4);
  float* biasPF  = (float*)alloc(2048);
  float* biasCF  = (float*)alloc(2048);
  u16* qT   = (u16*)alloc(2097152);
  u16* pc   = (u16*)alloc(8388608);
  u16* pcT  = (u16*)alloc(8388608);
  u16* vp   = (u16*)alloc(8388608);
  u16* rpT  = (u16*)alloc(8388608);
  u16* qc   = (u16*)alloc(8388608);
  u16* rc   = (u16*)alloc(8388608);
  u16* kT   = (u16*)alloc(2097152);
  u16* pad  = (u16*)alloc((size_t)2 * 4736 * 512 * 2);
  u16* vcT  = (u16*)alloc(8388608);
  u16* attnc = (u16*)alloc(1048576);
  float* lpart = (float*)alloc(131072);
  float* epart = (float*)pcT;   // [B][4][512][512] f32 = 8MB over pcT (dead after kT)

  const dim3 blk(256);

  hipMemsetAsync(pad, 0, (size_t)2 * 4736 * 512 * 2, stream);
  // merged prologue: transpose (4096 blocks) + prep (2048 blocks, full parallelism)
  k_pre<<<dim3(6144), blk, 0, stream>>>(x, xbT,
                                        wq_p, wpc, spc, wv, wrp, srp, wq_c, wrc, src_,
                                        wk, wpf, spf, wcf, scf,
                                        bq_p, bpc, tpc, bv, brp, trp, bq_c, brc, trc,
                                        bpf, tpf, bcf, tcf,
                                        Wall, wpfb, wcfb, wkb, biasAll, biasPF, biasCF);

  // fused 1x1: ONE GEMM [2688 x 4096] K=2048, router epilogue — 512-thread blocks
  {
    Epi e{}; e.bias = biasAll; e.mode = 1;
    e.f_qT = qT; e.f_pc = pc; e.f_pcT = pcT; e.f_vp = vp; e.f_rpT = rpT; e.f_qc = qc; e.f_rc = rc;
    gemm_bt<128, 512><<<dim3(21, 32, 2), dim3(512), 0, stream>>>(Wall, 2048, 0, xbT, 2048,
                                                                 4096L * 2048, 2048, 0, 1, e);
  }

  // kT[n][kc] = pcT * wk^T
  {
    Epi e{}; e.outb = kT; e.ldo = 128; e.outb_bs = 4096L * 128;
    gemm_bt<64, 256><<<dim3(32, 2, 2), blk, 0, stream>>>(pcT, 512, 4096L * 512, wkb, 512, 0,
                                                         512, 0, 1, e);
  }

  // flash attention (bf16 partials)
  k_flash<<<dim3(256), dim3(512), 0, stream>>>(qT, kT, vp, opart, lpart);
  k_combine_p<<<dim3(2048), blk, 0, stream>>>(opart, lpart, rpT, gamma_p, pad + 128 * 512);

  // conv3x3 #1: BN=128 x 512 threads, mode 3 — outp f32 un-pad + vcT bounce
  {
    Epi e{}; e.bias = biasPF; e.mode = 3; e.outu = outp; e.outt = vcT;
    gemm_bt<128, 512><<<dim3(4, 35, 2), dim3(512), 0, stream>>>(wpfb, 4608, 0, pad + 128 * 512,
                                                                512, 4736L * 512, 4608, 1, 1, e);
  }

  // energy = qc @ pc^T, split-K=4, f32 partials
  {
    Epi e{}; e.outf = epart; e.ldof = 512; e.outf_bs = 512L * 512;
    gemm_bt<64, 256><<<dim3(4, 8, 8), blk, 0, stream>>>(qc, 4096, 512L * 4096, pc, 4096,
                                                        512L * 4096, 4096, 0, 4, e);
  }
  k_softmax_chan<<<dim3(1024), dim3(64), 0, stream>>>(epart, attnc);

  // out_c_pre = gamma_c*(attnc @ v_cT^T) + rc -> pad (BN=128 x 512 thr, mode 2 bounce)
  {
    Epi e{}; e.alpha_ptr = gamma_c; e.mode = 2;
    e.add = rc; e.ld_add = 4096; e.add_bs = 512L * 4096;
    e.outt = pad + 128 * 512; e.ldot = 512; e.outt_bs = 4736L * 512;
    gemm_bt<128, 512><<<dim3(4, 32, 2), dim3(512), 0, stream>>>(attnc, 512, 512L * 512, vcT, 512,
                                                                4096L * 512, 512, 0, 1, e);
  }

  // conv3x3 #2: BN=128 x 512 threads, direct un-pad f32 store into d_out
  {
    Epi e{}; e.bias = biasCF; e.relu = 1; e.outu = outc;
    gemm_bt<128, 512><<<dim3(4, 35, 2), dim3(512), 0, stream>>>(wcfb, 4608, 0, pad + 128 * 512,
                                                                512, 4736L * 512, 4608, 1, 1, e);
  }
}

// Round 23
// 421.134 us; speedup vs baseline: 1.0046x; 1.0046x over previous
//
#include <hip/hip_runtime.h>
#include <hip/hip_bf16.h>
#include <stdint.h>

typedef unsigned short u16;
typedef short bf16x8 __attribute__((ext_vector_type(8)));
typedef short s16x4 __attribute__((ext_vector_type(4)));
typedef float f32x4 __attribute__((ext_vector_type(4)));

#define DEV static __device__ __forceinline__

DEV float b2f(u16 u) { return __uint_as_float(((unsigned)u) << 16); }
DEV u16 f2bu(float x) {
  union { __hip_bfloat16 h; u16 u; } c;
  c.h = __float2bfloat16(x);
  return c.u;
}

DEV void gload16(const void* g, void* l) {
  __builtin_amdgcn_global_load_lds(
      (const __attribute__((address_space(1))) void*)(uintptr_t)g,
      (__attribute__((address_space(3))) void*)(uintptr_t)l, 16, 0, 0);
}

struct Epi {
  const float* bias;
  const float* alpha_ptr;
  const u16* add;
  long ld_add, add_bs;
  int relu;
  u16* outb; long ldo;  long outb_bs;
  int padrow;
  u16* outt; long ldot; long outt_bs;
  int padmap;
  float* outf; long ldof; long outf_bs;
  float* outu;
  int mode;  // 1=fused router; 2=attnV bounce->pad; 3=conv1 (outp f32 unpad + vcT bounce)
  u16 *f_qT, *f_pc, *f_pcT, *f_vp, *f_rpT, *f_qc, *f_rc;
};

// ============ ring-pipelined 128xBN GEMM: D[M][N] = A[M][K] * Bt[N][K]^T ============
// 3-slot LDS ring + counted vmcnt; one raw s_barrier/K-step; vmcnt never 0 until last.
// XOR-swizzled LDS (0 conflicts), bijective XCD chunking GROUP=8 (proven; 32 regressed),
// TPB=512: 8 waves (R13/R14). All epilogues LDS-bounced for 16B stores.
// Converged config (R17/R20-R22): RING 4 null, GROUP 32 worse, split-K worse, setprio null.
template <int BN, int TPB>
__global__ __launch_bounds__(TPB) void gemm_bt(
    const u16* __restrict__ A, long lda, long a_bs,
    const u16* __restrict__ Bt, long ldb, long b_bs,
    int K, int conv9, int zdiv, Epi e)
{
  constexpr int WAVES = TPB / 64;
  constexpr int NW_N = (WAVES == 8) ? 4 : 2;
  constexpr int WCOLS = BN / NW_N;
  constexpr int FNW = WCOLS / 16;
  constexpr int AG = 512 / TPB;
  constexpr int BG = (BN * 4) / TPB;
  constexpr int LPS = AG + BG;
  constexpr int SLOT = 4096 + BN * 32;
  __shared__ u16 SMEM[3 * SLOT];

  const int bz = blockIdx.z;
  int batch = bz, ksteps = K >> 5, ksbase = 0;
  if (zdiv > 1) {
    batch = bz / zdiv;
    int sl = bz - batch * zdiv;
    ksteps = (K / zdiv) >> 5;
    ksbase = sl * ksteps;
  }
  const int gx = gridDim.x, gy = gridDim.y;
  const int nwg = gx * gy;
  const int orig = blockIdx.y * gx + blockIdx.x;
  const int q8 = nwg >> 3, r8 = nwg & 7;
  const int xcd = orig & 7, lid = orig >> 3;
  const int wgid = (xcd < r8 ? xcd * (q8 + 1) : r8 * (q8 + 1) + (xcd - r8) * q8) + lid;
  const int GROUP = 8;
  const int span = GROUP * gy;
  const int group_id = wgid / span;
  const int first_m = group_id * GROUP;
  const int gsz = (GROUP < gx - first_m) ? GROUP : (gx - first_m);
  const int rem = wgid - group_id * span;
  const int bm = first_m + rem % gsz;
  const int bn = rem / gsz;

  const u16* Ab = A + (long)batch * a_bs;
  const u16* Bb = Bt + (long)batch * b_bs;
  const int m0 = bm * 128;
  const int n0 = bn * BN;
  const int t = threadIdx.x;
  const int w = t >> 6, l = t & 63;
  const int wr = w / NW_N, wc = w % NW_N;
  const int lr = l & 15, lg = l >> 4;

  f32x4 acc[4][FNW];
#pragma unroll
  for (int i = 0; i < 4; ++i)
#pragma unroll
    for (int j = 0; j < FNW; ++j) acc[i][j] = (f32x4){0.f, 0.f, 0.f, 0.f};

  auto stage = [&](int ks, int slot) {
    u16* As = SMEM + slot * SLOT;
    u16* Bs = As + 4096;
    const int k0 = ks << 5;
    long brow = 0;
    int bk0 = k0;
    if (conv9) {
      int s = k0 >> 9;
      int kh = s / 3, kw = s - kh * 3;
      brow = (long)((kh - 1) * 66 + (kw - 1));
      bk0 = k0 & 511;
    }
#pragma unroll
    for (int r = 0; r < AG; ++r) {
      int idx = r * TPB + t;
      int row = idx >> 2;
      int ko = (((idx & 3) ^ ((row >> 1) & 3)) << 3);
      gload16(Ab + (long)(m0 + row) * lda + (k0 + ko),
              (char*)As + ((r * TPB + (t & (TPB - 64))) << 4));
    }
#pragma unroll
    for (int r = 0; r < BG; ++r) {
      int idx = r * TPB + t;
      int row = idx >> 2;
      int ko = (((idx & 3) ^ ((row >> 1) & 3)) << 3);
      gload16(Bb + ((long)(n0 + row) + brow) * ldb + (bk0 + ko),
              (char*)Bs + ((r * TPB + (t & (TPB - 64))) << 4));
    }
  };

  auto compute = [&](int slot) {
    const u16* As = SMEM + slot * SLOT;
    const u16* Bs = As + 4096;
    __builtin_amdgcn_s_setprio(1);
    bf16x8 af[4], bfr[FNW];
#pragma unroll
    for (int i = 0; i < 4; ++i) {
      int row = wr * 64 + i * 16 + lr;
      int cg = lg ^ ((row >> 1) & 3);
      af[i] = *(const bf16x8*)(As + row * 32 + cg * 8);
    }
#pragma unroll
    for (int j = 0; j < FNW; ++j) {
      int row = wc * WCOLS + j * 16 + lr;
      int cg = lg ^ ((row >> 1) & 3);
      bfr[j] = *(const bf16x8*)(Bs + row * 32 + cg * 8);
    }
#pragma unroll
    for (int i = 0; i < 4; ++i)
#pragma unroll
      for (int j = 0; j < FNW; ++j)
        acc[i][j] = __builtin_amdgcn_mfma_f32_16x16x32_bf16(af[i], bfr[j], acc[i][j], 0, 0, 0);
    __builtin_amdgcn_s_setprio(0);
  };

  const int nk = ksteps;
  stage(ksbase, 0);
  if (nk > 1) stage(ksbase + 1, 1);
  for (int tt = 0; tt < nk; ++tt) {
    if (tt < nk - 1) {
      if constexpr (LPS == 4) asm volatile("s_waitcnt vmcnt(4)" ::: "memory");
      else if constexpr (LPS == 3) asm volatile("s_waitcnt vmcnt(3)" ::: "memory");
      else asm volatile("s_waitcnt vmcnt(2)" ::: "memory");
    } else {
      asm volatile("s_waitcnt vmcnt(0)" ::: "memory");
    }
    __builtin_amdgcn_s_barrier();
    if (tt + 2 < nk) stage(ksbase + tt + 2, (tt + 2) % 3);
    compute(tt % 3);
    asm volatile("s_waitcnt lgkmcnt(0)" ::: "memory");
  }

  const float alpha = e.alpha_ptr ? e.alpha_ptr[0] : 1.0f;

  if (e.mode == 1) {
    const int seg = (m0 < 128) ? 0 : (m0 < 640) ? 1 : (m0 < 1152) ? 2 :
                    (m0 < 1664) ? 3 : (m0 < 2176) ? 4 : 5;
    const bool doT = (seg == 0 || seg == 1 || seg == 3);
    const bool doR = (seg == 1 || seg == 2 || seg == 4 || seg == 5);
    const bool doRelu = (seg == 1 || seg == 3 || seg == 5);

    if (doT) {
      __syncthreads();
#pragma unroll
      for (int i = 0; i < 4; ++i) {
#pragma unroll
        for (int j = 0; j < FNW; ++j) {
          const int gnl = wc * WCOLS + j * 16 + lr;
#pragma unroll
          for (int q = 0; q < 4; ++q) {
            const int gml = wr * 64 + i * 16 + lg * 4 + q;
            float v = acc[i][j][q] + e.bias[m0 + gml];
            if (doRelu) v = fmaxf(v, 0.f);
            SMEM[gnl * 128 + (((gml >> 3) ^ (gnl & 7)) << 3) + (gml & 7)] = f2bu(v);
          }
        }
      }
      __syncthreads();
      u16* dst; long ld;
      if (seg == 0)      { dst = e.f_qT  + ((long)batch * 4096 + n0) * 128;                ld = 128; }
      else if (seg == 1) { dst = e.f_pcT + ((long)batch * 4096 + n0) * 512 + (m0 - 128);   ld = 512; }
      else               { dst = e.f_rpT + ((long)batch * 4096 + n0) * 512 + (m0 - 1152);  ld = 512; }
#pragma unroll
      for (int k = 0; k < (BN * 16) / TPB; ++k) {
        int chunk = k * TPB + t;
        int row = chunk >> 4, c16 = chunk & 15;
        bf16x8 vv = *(const bf16x8*)(SMEM + row * 128 + ((c16 ^ (row & 7)) << 3));
        *(bf16x8*)(dst + (long)row * ld + c16 * 8) = vv;
      }
    }
    if (doR) {
      __syncthreads();
#pragma unroll
      for (int i = 0; i < 4; ++i) {
#pragma unroll
        for (int j = 0; j < FNW; ++j) {
          const int gnl = wc * WCOLS + j * 16 + lr;
#pragma unroll
          for (int q = 0; q < 4; ++q) {
            const int gml = wr * 64 + i * 16 + lg * 4 + q;
            float v = acc[i][j][q] + e.bias[m0 + gml];
            if (doRelu) v = fmaxf(v, 0.f);
            SMEM[gml * 128 + (((gnl >> 3) ^ (gml & 7)) << 3) + (gnl & 7)] = f2bu(v);
          }
        }
      }
      __syncthreads();
      const int mb = (seg == 1) ? 128 : (seg == 2) ? 640 : (seg == 4) ? 1664 : 2176;
      u16* rbase = (seg == 1) ? e.f_pc : (seg == 2) ? e.f_vp : (seg == 4) ? e.f_qc : e.f_rc;
      u16* rdst = rbase + ((long)batch * 512 + (m0 - mb)) * 4096 + n0;
#pragma unroll
      for (int k = 0; k < (BN * 16) / TPB; ++k) {
        int chunk = k * TPB + t;
        int row = chunk >> 4, c16 = chunk & 15;
        bf16x8 vv = *(const bf16x8*)(SMEM + row * 128 + ((c16 ^ (row & 7)) << 3));
        *(bf16x8*)(rdst + (long)row * 4096 + c16 * 8) = vv;
      }
    }
    return;
  }

  if (e.mode == 2) {
    __syncthreads();
#pragma unroll
    for (int i = 0; i < 4; ++i) {
#pragma unroll
      for (int j = 0; j < FNW; ++j) {
        const int gn = n0 + wc * WCOLS + j * 16 + lr;
#pragma unroll
        for (int q = 0; q < 4; ++q) {
          const int gm = m0 + wr * 64 + i * 16 + lg * 4 + q;
          float v = acc[i][j][q] * alpha +
                    b2f(e.add[(long)batch * e.add_bs + (long)gm * e.ld_add + gn]);
          const int gnl = gn - n0, gml = gm - m0;
          SMEM[gnl * 128 + (((gml >> 3) ^ (gnl & 7)) << 3) + (gml & 7)] = f2bu(v);
        }
      }
    }
    __syncthreads();
#pragma unroll
    for (int k = 0; k < (BN * 16) / TPB; ++k) {
      int chunk = k * TPB + t;
      int row = chunk >> 4, c16 = chunk & 15;
      int gnr = n0 + row;
      long rowo = (long)((gnr >> 6) + 1) * 66 + (gnr & 63) + 1;
      bf16x8 vv = *(const bf16x8*)(SMEM + row * 128 + ((c16 ^ (row & 7)) << 3));
      *(bf16x8*)(e.outt + (long)batch * e.outt_bs + rowo * e.ldot + m0 + c16 * 8) = vv;
    }
    return;
  }

  if (e.mode == 3) {
    __syncthreads();
#pragma unroll
    for (int i = 0; i < 4; ++i) {
#pragma unroll
      for (int j = 0; j < FNW; ++j) {
        const int gn = n0 + wc * WCOLS + j * 16 + lr;
#pragma unroll
        for (int q = 0; q < 4; ++q) {
          const int gm = m0 + wr * 64 + i * 16 + lg * 4 + q;
          float v = fmaxf(acc[i][j][q] + e.bias[gm], 0.f);
          int ph = gn / 66, pw = gn - ph * 66;
          if (ph >= 1 && ph <= 64 && pw >= 1 && pw <= 64)
            e.outu[(long)batch * 2097152 + (long)gm * 4096 + (ph - 1) * 64 + (pw - 1)] = v;
          const int gnl = gn - n0, gml = gm - m0;
          SMEM[gnl * 128 + (((gml >> 3) ^ (gnl & 7)) << 3) + (gml & 7)] = f2bu(v);
        }
      }
    }
    __syncthreads();
#pragma unroll
    for (int k = 0; k < (BN * 16) / TPB; ++k) {
      int chunk = k * TPB + t;
      int row = chunk >> 4, c16 = chunk & 15;
      int gnr = n0 + row;
      int ph = gnr / 66, pw = gnr - ph * 66;
      if (ph >= 1 && ph <= 64 && pw >= 1 && pw <= 64) {
        long nn = (long)(ph - 1) * 64 + (pw - 1);
        bf16x8 vv = *(const bf16x8*)(SMEM + row * 128 + ((c16 ^ (row & 7)) << 3));
        *(bf16x8*)(e.outt + ((long)batch * 4096 + nn) * 512 + m0 + c16 * 8) = vv;
      }
    }
    return;
  }

#pragma unroll
  for (int i = 0; i < 4; ++i) {
#pragma unroll
    for (int j = 0; j < FNW; ++j) {
      const int gn = n0 + wc * WCOLS + j * 16 + lr;
#pragma unroll
      for (int q = 0; q < 4; ++q) {
        const int gm = m0 + wr * 64 + i * 16 + lg * 4 + q;
        float v = acc[i][j][q] * alpha;
        if (e.bias) v += e.bias[gm];
        if (e.add) v += b2f(e.add[(long)batch * e.add_bs + (long)gm * e.ld_add + gn]);
        if (e.relu) v = fmaxf(v, 0.f);
        if (e.outb) {
          long rowo = gm;
          if (e.padrow) rowo = (long)((gm >> 6) + 1) * 66 + (gm & 63) + 1;
          e.outb[(long)batch * e.outb_bs + rowo * e.ldo + gn] = f2bu(v);
        }
        if (e.outf)
          e.outf[(long)bz * e.outf_bs + (long)gm * e.ldof + gn] = v;
        if (e.outu) {
          int ph = gn / 66, pw = gn - ph * 66;
          if (ph >= 1 && ph <= 64 && pw >= 1 && pw <= 64)
            e.outu[(long)batch * 2097152 + (long)gm * 4096 + (ph - 1) * 64 + (pw - 1)] = v;
        }
        if (e.outt) {
          long rt = gn;
          if (e.padmap) rt = (long)((gn >> 6) + 1) * 66 + (gn & 63) + 1;
          e.outt[(long)batch * e.outt_bs + rt * e.ldot + gm] = f2bu(v);
        }
      }
    }
  }
}

// ---------------- flash attention (position branch), bf16 O-partials ----------------
__global__ __launch_bounds__(512, 2) void k_flash(
    const u16* __restrict__ qT, const u16* __restrict__ kT,
    const u16* __restrict__ vp,
    u16* __restrict__ opart, float* __restrict__ lpart)
{
  __shared__ u16 kt_lds[2][64 * 128];
  __shared__ u16 p_lds[128 * 64];

  const int orig = blockIdx.x;
  const int xcd = orig & 7;
  const int qtile = orig >> 3;
  const int split = xcd & 3;
  const int b = xcd >> 2;

  const int t = threadIdx.x;
  const int w = t >> 6;
  const int l = t & 63;
  const int lr = l & 15, lg = l >> 4;
  const int n0 = qtile * 128;
  const int m_base = split * 1024;

  const u16* qb = qT + ((long)b * 4096 + n0 + w * 16) * 128;
  const u16* kb = kT + ((long)b * 4096 + m_base) * 128;

  bf16x8 qf[4];
#pragma unroll
  for (int ks = 0; ks < 4; ++ks)
    qf[ks] = *(const bf16x8*)(qb + (long)lr * 128 + ks * 32 + lg * 8);

  f32x4 acc[8][4];
#pragma unroll
  for (int i = 0; i < 8; ++i)
#pragma unroll
    for (int j = 0; j < 4; ++j) acc[i][j] = (f32x4){0.f, 0.f, 0.f, 0.f};
  float lrun[4] = {0.f, 0.f, 0.f, 0.f};

  auto stage = [&](int mt, int buf) {
#pragma unroll
    for (int r = 0; r < 2; ++r) {
      int idx = (r << 9) + t;
      int row = idx >> 4;
      int g = idx & 15;
      int gs = g ^ (row & 7);
      gload16(kb + ((long)(mt * 64 + row)) * 128 + gs * 8,
              (char*)(&kt_lds[buf][0]) + (((r << 9) + (t & 448)) << 4));
    }
  };

  stage(0, 0);
  __syncthreads();

  const int nt = 16;
  for (int mt = 0; mt < nt; ++mt) {
    const int cur = mt & 1;
    if (mt + 1 < nt) stage(mt + 1, cur ^ 1);

    bf16x8 vv[4][2];
#pragma unroll
    for (int cs = 0; cs < 4; ++cs) {
#pragma unroll
      for (int k2 = 0; k2 < 2; ++k2) {
        const u16* va = vp + ((long)b * 512 + w * 64 + cs * 16 + lr) * 4096 +
                        m_base + mt * 64 + k2 * 32 + lg * 8;
        vv[cs][k2] = *(const bf16x8*)va;
      }
    }

    f32x4 sacc[4];
#pragma unroll
    for (int ms = 0; ms < 4; ++ms) sacc[ms] = (f32x4){0.f, 0.f, 0.f, 0.f};
#pragma unroll
    for (int ms = 0; ms < 4; ++ms) {
#pragma unroll
      for (int ks = 0; ks < 4; ++ks) {
        int row = ms * 16 + lr;
        int gs = (ks * 4 + lg) ^ (row & 7);
        bf16x8 kf = *(const bf16x8*)(&kt_lds[cur][0] + row * 128 + gs * 8);
        sacc[ms] = __builtin_amdgcn_mfma_f32_16x16x32_bf16(qf[ks], kf, sacc[ms], 0, 0, 0);
      }
    }

    float rs[4] = {0.f, 0.f, 0.f, 0.f};
#pragma unroll
    for (int ms = 0; ms < 4; ++ms) {
#pragma unroll
      for (int q = 0; q < 4; ++q) {
        float p = __expf(sacc[ms][q]);
        rs[q] += p;
        int prow = w * 16 + 4 * lg + q;
        int m = ms * 16 + lr;
        int gm = m >> 3, offm = m & 7;
        int gsm = gm ^ (prow & 7);
        p_lds[prow * 64 + gsm * 8 + offm] = f2bu(p);
      }
    }
#pragma unroll
    for (int q = 0; q < 4; ++q) {
      rs[q] += __shfl_xor(rs[q], 1);
      rs[q] += __shfl_xor(rs[q], 2);
      rs[q] += __shfl_xor(rs[q], 4);
      rs[q] += __shfl_xor(rs[q], 8);
      lrun[q] += rs[q];
    }

    __syncthreads();

    __builtin_amdgcn_s_setprio(1);
#pragma unroll
    for (int ntl = 0; ntl < 8; ++ntl) {
      int row = ntl * 16 + lr;
      int gs0 = (0 * 4 + lg) ^ (row & 7);
      int gs1 = (1 * 4 + lg) ^ (row & 7);
      bf16x8 pf0 = *(const bf16x8*)(&p_lds[0] + row * 64 + gs0 * 8);
      bf16x8 pf1 = *(const bf16x8*)(&p_lds[0] + row * 64 + gs1 * 8);
#pragma unroll
      for (int cs = 0; cs < 4; ++cs) {
        acc[ntl][cs] = __builtin_amdgcn_mfma_f32_16x16x32_bf16(pf0, vv[cs][0], acc[ntl][cs], 0, 0, 0);
        acc[ntl][cs] = __builtin_amdgcn_mfma_f32_16x16x32_bf16(pf1, vv[cs][1], acc[ntl][cs], 0, 0, 0);
      }
    }
    __builtin_amdgcn_s_setprio(0);
    __syncthreads();
  }

  const long pbase = ((long)split * 2 + b) * 4096;
  if (lr == 0) {
#pragma unroll
    for (int q = 0; q < 4; ++q)
      lpart[pbase + n0 + w * 16 + 4 * lg + q] = lrun[q];
  }
#pragma unroll
  for (int ntl = 0; ntl < 8; ++ntl) {
#pragma unroll
    for (int cs = 0; cs < 4; ++cs) {
#pragma unroll
      for (int q = 0; q < 4; ++q) {
        long row = n0 + ntl * 16 + 4 * lg + q;
        int col = w * 64 + cs * 16 + lr;
        opart[(pbase + row) * 512 + col] = f2bu(acc[ntl][cs][q]);
      }
    }
  }
}

__global__ __launch_bounds__(256) void k_combine_p(
    const u16* __restrict__ opart, const float* __restrict__ lpart,
    const u16* __restrict__ rpT, const float* __restrict__ gamma_p,
    u16* __restrict__ padi)
{
  const int t = threadIdx.x;
  const long rg = (long)blockIdx.x * 4 + (t >> 6);
  const int b = (int)(rg >> 12), n = (int)(rg & 4095);
  const int l = t & 63;
  const int c0 = l * 8;
  float lsum = 0.f;
#pragma unroll
  for (int s = 0; s < 4; ++s) lsum += lpart[((long)s * 2 + b) * 4096 + n];
  float o[8];
#pragma unroll
  for (int i = 0; i < 8; ++i) o[i] = 0.f;
#pragma unroll
  for (int s = 0; s < 4; ++s) {
    const u16* op = opart + ((((long)s * 2 + b) * 4096 + n) * 512) + c0;
    bf16x8 a = *(const bf16x8*)op;
#pragma unroll
    for (int i = 0; i < 8; ++i) o[i] += b2f((u16)a[i]);
  }
  const float g = gamma_p[0];
  const float inv = 1.0f / lsum;
  bf16x8 rv = *(const bf16x8*)(rpT + ((long)b * 4096 + n) * 512 + c0);
  bf16x8 outv;
#pragma unroll
  for (int i = 0; i < 8; ++i)
    outv[i] = (short)f2bu(g * o[i] * inv + b2f((u16)rv[i]));
  const int h = n >> 6, ww = n & 63;
  *(bf16x8*)(padi + ((long)b * 4736 + (long)(h + 1) * 66 + ww + 1) * 512 + c0) = outv;
}

// ---- merged prologue: blocks [0,4096) transpose x; blocks [4096,6144) weight prep ----
__global__ __launch_bounds__(256) void k_pre(
    const float* __restrict__ x, u16* __restrict__ xt,
    const float* wq_p, const float* wpc, const float* spc,
    const float* wv, const float* wrp, const float* srp,
    const float* wq_c, const float* wrc, const float* src_,
    const float* wk, const float* wpf, const float* spf,
    const float* wcf, const float* scf,
    const float* bq_p, const float* bpc, const float* tpc,
    const float* bv, const float* brp, const float* trp,
    const float* bq_c, const float* brc, const float* trc,
    const float* bpf, const float* tpf,
    const float* bcf, const float* tcf,
    u16* wall, u16* wpfb, u16* wcfb, u16* wkb,
    float* biasAll, float* biasPF, float* biasCF)
{
  const int bid = blockIdx.x;
  const int t = threadIdx.x;

  if (bid < 4096) {
    __shared__ float tile[64][65];
    const int b = bid >> 11;
    const int remb = bid & 2047;
    const int c0 = (remb & 31) * 64;
    const int n0 = (remb >> 5) * 64;
    const int tn = t & 63, tc = t >> 6;
    const float* xp = x + ((long)b * 2048 + c0) * 4096 + n0;
#pragma unroll
    for (int i = 0; i < 16; ++i)
      tile[tc + i * 4][tn] = xp[(long)(tc + i * 4) * 4096 + tn];
    __syncthreads();
    u16* xo = xt + ((long)b * 4096 + n0) * 2048 + c0;
#pragma unroll
    for (int i = 0; i < 2; ++i) {
      int chunk = i * 256 + t;
      int n = chunk >> 3, c8 = chunk & 7;
      bf16x8 o;
#pragma unroll
      for (int j = 0; j < 8; ++j) o[j] = (short)f2bu(tile[c8 * 8 + j][n]);
      *(bf16x8*)(xo + (long)n * 2048 + c8 * 8) = o;
    }
    return;
  }

  // ---- weight/bias prep, grid-stride over 2048 blocks (full standalone parallelism) ----
  const long W4 = (2688L * 2048) / 4;
  const long W3 = 512L * 512 * 9;
  const long TOT = W4 + 2 * W3 + 65536 + 3712;
  for (long i = (long)(bid - 4096) * 256 + t; i < TOT; i += 2048L * 256) {
    if (i < W4) {
      long i4 = i << 2;
      int r = (int)(i4 >> 11), c = (int)(i4 & 2047);
      const float* base; float s = 1.f;
      if (r < 128)       { base = wq_p + (long)r * 2048; }
      else if (r < 640)  { int rr = r - 128;  base = wpc + (long)rr * 2048; s = spc[rr]; }
      else if (r < 1152) { int rr = r - 640;  base = wv  + (long)rr * 2048; }
      else if (r < 1664) { int rr = r - 1152; base = wrp + (long)rr * 2048; s = srp[rr]; }
      else if (r < 2176) { int rr = r - 1664; base = wq_c + (long)rr * 2048; }
      else               { int rr = r - 2176; base = wrc + (long)rr * 2048; s = src_[rr]; }
      f32x4 v = *(const f32x4*)(base + c);
      s16x4 o;
#pragma unroll
      for (int j = 0; j < 4; ++j) o[j] = (short)f2bu(s * v[j]);
      *(s16x4*)(wall + i4) = o;
    } else if (i < W4 + 2 * W3) {
      int which = (i < W4 + W3) ? 0 : 1;
      long j = i - W4 - (long)which * W3;
      int o = (int)(j / (512 * 9));
      long rem = j - (long)o * (512 * 9);
      int khw = (int)(rem >> 9);
      int c = (int)(rem & 511);
      int kh = khw / 3, kw = khw - kh * 3;
      const float* wsrc = which ? wcf : wpf;
      const float* ssrc = which ? scf : spf;
      u16* dst = which ? wcfb : wpfb;
      dst[j] = f2bu(ssrc[o] * wsrc[(((long)o * 512 + c) * 3 + kh) * 3 + kw]);
    } else if (i < W4 + 2 * W3 + 65536) {
      long j = i - W4 - 2 * W3;
      wkb[j] = f2bu(wk[j]);
    } else {
      long j = i - W4 - 2 * W3 - 65536;
      if (j < 2688) {
        int r = (int)j;
        float v;
        if (r < 128) v = bq_p[r];
        else if (r < 640)  { int k = r - 128;  v = spc[k] * bpc[k] + tpc[k]; }
        else if (r < 1152) { int k = r - 640;  v = bv[k]; }
        else if (r < 1664) { int k = r - 1152; v = srp[k] * brp[k] + trp[k]; }
        else if (r < 2176) { int k = r - 1664; v = bq_c[k]; }
        else               { int k = r - 2176; v = src_[k] * brc[k] + trc[k]; }
        biasAll[r] = v;
      } else if (j < 3200) {
        int k = (int)(j - 2688);
        biasPF[k] = spf[k] * bpf[k] + tpf[k];
      } else {
        int k = (int)(j - 3200);
        biasCF[k] = scf[k] * bcf[k] + tcf[k];
      }
    }
  }
}

// ---- channel softmax summing 4 split-K slices ----
__global__ void k_softmax_chan(const float* __restrict__ EP, u16* __restrict__ A) {
  const long row = blockIdx.x;
  const int batch = (int)(row >> 9), r = (int)(row & 511);
  const int l = threadIdx.x;
  float v[8];
#pragma unroll
  for (int i = 0; i < 8; ++i) v[i] = 0.f;
  for (int s = 0; s < 4; ++s) {
    const float* e = EP + (((long)batch * 4 + s) * 512 + r) * 512 + l * 8;
#pragma unroll
    for (int i = 0; i < 8; ++i) v[i] += e[i];
  }
  float mn = 1e30f;
#pragma unroll
  for (int i = 0; i < 8; ++i) mn = fminf(mn, v[i]);
  for (int o = 32; o > 0; o >>= 1) mn = fminf(mn, __shfl_xor(mn, o));
  float s = 0.f;
#pragma unroll
  for (int i = 0; i < 8; ++i) { v[i] = __expf(mn - v[i]); s += v[i]; }
  for (int o = 32; o > 0; o >>= 1) s += __shfl_xor(s, o);
  const float inv = 1.0f / s;
  u16* out = A + row * 512;
#pragma unroll
  for (int i = 0; i < 8; ++i) out[l * 8 + i] = f2bu(v[i] * inv);
}

// =======================================================================================
extern "C" void kernel_launch(void* const* d_in, const int* in_sizes, int n_in,
                              void* d_out, int out_size, void* d_ws, size_t ws_size,
                              hipStream_t stream) {
  (void)in_sizes; (void)n_in; (void)out_size;
  const float* x     = (const float*)d_in[0];
  const float* wq_p  = (const float*)d_in[1];
  const float* bq_p  = (const float*)d_in[2];
  const float* wpc   = (const float*)d_in[3];
  const float* bpc   = (const float*)d_in[4];
  const float* spc   = (const float*)d_in[5];
  const float* tpc   = (const float*)d_in[6];
  const float* wk    = (const float*)d_in[7];
  const float* wv    = (const float*)d_in[9];
  const float* bv    = (const float*)d_in[10];
  const float* wrp   = (const float*)d_in[11];
  const float* brp   = (const float*)d_in[12];
  const float* srp   = (const float*)d_in[13];
  const float* trp   = (const float*)d_in[14];
  const float* wpf   = (const float*)d_in[15];
  const float* bpf   = (const float*)d_in[16];
  const float* spf   = (const float*)d_in[17];
  const float* tpf   = (const float*)d_in[18];
  const float* gamma_p = (const float*)d_in[19];
  const float* wq_c  = (const float*)d_in[20];
  const float* bq_c  = (const float*)d_in[21];
  const float* wrc   = (const float*)d_in[22];
  const float* brc   = (const float*)d_in[23];
  const float* src_  = (const float*)d_in[24];
  const float* trc   = (const float*)d_in[25];
  const float* wcf   = (const float*)d_in[26];
  const float* bcf   = (const float*)d_in[27];
  const float* scf   = (const float*)d_in[28];
  const float* tcf   = (const float*)d_in[29];
  const float* gamma_c = (const float*)d_in[30];

  float* outc = (float*)d_out;
  float* outp = outc + 4194304;

  if (ws_size < 151000000ULL) return;

  char* ws = (char*)d_ws;
  size_t off = 0;
  auto alloc = [&](size_t sz) { void* p = ws + off; off += (sz + 255) & ~(size_t)255; return p; };

  char* region0 = (char*)alloc(67108864);
  u16* xbT     = (u16*)region0;                 // [B][4096][2048]
  u16* Wall    = (u16*)(region0 + 33554432);    // [2688][2048]
  u16* wkb     = (u16*)(region0 + 44564480);    // [128][512]
  u16* opart   = (u16*)region0;                 // [4][B][4096][512] bf16 (33.5MB)
  u16* wpfb  = (u16*)alloc(4718592);
  u16* wcfb  = (u16*)alloc(4718592);
  float* biasAll = (float*)alloc(2688 * 4);
  float* biasPF  = (float*)alloc(2048);
  float* biasCF  = (float*)alloc(2048);
  u16* qT   = (u16*)alloc(2097152);
  u16* pc   = (u16*)alloc(8388608);
  u16* pcT  = (u16*)alloc(8388608);
  u16* vp   = (u16*)alloc(8388608);
  u16* rpT  = (u16*)alloc(8388608);
  u16* qc   = (u16*)alloc(8388608);
  u16* rc   = (u16*)alloc(8388608);
  u16* kT   = (u16*)alloc(2097152);
  u16* pad  = (u16*)alloc((size_t)2 * 4736 * 512 * 2);
  u16* vcT  = (u16*)alloc(8388608);
  u16* attnc = (u16*)alloc(1048576);
  float* lpart = (float*)alloc(131072);
  float* epart = (float*)pcT;   // [B][4][512][512] f32 = 8MB over pcT (dead after kT)

  const dim3 blk(256);

  hipMemsetAsync(pad, 0, (size_t)2 * 4736 * 512 * 2, stream);
  // merged prologue: transpose (4096 blocks) + prep (2048 blocks, full parallelism)
  k_pre<<<dim3(6144), blk, 0, stream>>>(x, xbT,
                                        wq_p, wpc, spc, wv, wrp, srp, wq_c, wrc, src_,
                                        wk, wpf, spf, wcf, scf,
                                        bq_p, bpc, tpc, bv, brp, trp, bq_c, brc, trc,
                                        bpf, tpf, bcf, tcf,
                                        Wall, wpfb, wcfb, wkb, biasAll, biasPF, biasCF);

  // fused 1x1: ONE GEMM [2688 x 4096] K=2048, router epilogue — 512-thread blocks
  {
    Epi e{}; e.bias = biasAll; e.mode = 1;
    e.f_qT = qT; e.f_pc = pc; e.f_pcT = pcT; e.f_vp = vp; e.f_rpT = rpT; e.f_qc = qc; e.f_rc = rc;
    gemm_bt<128, 512><<<dim3(21, 32, 2), dim3(512), 0, stream>>>(Wall, 2048, 0, xbT, 2048,
                                                                 4096L * 2048, 2048, 0, 1, e);
  }

  // kT[n][kc] = pcT * wk^T
  {
    Epi e{}; e.outb = kT; e.ldo = 128; e.outb_bs = 4096L * 128;
    gemm_bt<64, 256><<<dim3(32, 2, 2), blk, 0, stream>>>(pcT, 512, 4096L * 512, wkb, 512, 0,
                                                         512, 0, 1, e);
  }

  // flash attention (bf16 partials)
  k_flash<<<dim3(256), dim3(512), 0, stream>>>(qT, kT, vp, opart, lpart);
  k_combine_p<<<dim3(2048), blk, 0, stream>>>(opart, lpart, rpT, gamma_p, pad + 128 * 512);

  // conv3x3 #1: BN=128 x 512 threads, mode 3 — outp f32 un-pad + vcT bounce
  {
    Epi e{}; e.bias = biasPF; e.mode = 3; e.outu = outp; e.outt = vcT;
    gemm_bt<128, 512><<<dim3(4, 35, 2), dim3(512), 0, stream>>>(wpfb, 4608, 0, pad + 128 * 512,
                                                                512, 4736L * 512, 4608, 1, 1, e);
  }

  // energy = qc @ pc^T, split-K=4, f32 partials
  {
    Epi e{}; e.outf = epart; e.ldof = 512; e.outf_bs = 512L * 512;
    gemm_bt<64, 256><<<dim3(4, 8, 8), blk, 0, stream>>>(qc, 4096, 512L * 4096, pc, 4096,
                                                        512L * 4096, 4096, 0, 4, e);
  }
  k_softmax_chan<<<dim3(1024), dim3(64), 0, stream>>>(epart, attnc);

  // out_c_pre = gamma_c*(attnc @ v_cT^T) + rc -> pad (BN=128 x 512 thr, mode 2 bounce)
  {
    Epi e{}; e.alpha_ptr = gamma_c; e.mode = 2;
    e.add = rc; e.ld_add = 4096; e.add_bs = 512L * 4096;
    e.outt = pad + 128 * 512; e.ldot = 512; e.outt_bs = 4736L * 512;
    gemm_bt<128, 512><<<dim3(4, 32, 2), dim3(512), 0, stream>>>(attnc, 512, 512L * 512, vcT, 512,
                                                                4096L * 512, 512, 0, 1, e);
  }

  // conv3x3 #2: BN=128 x 512 threads, direct un-pad f32 store into d_out
  {
    Epi e{}; e.bias = biasCF; e.relu = 1; e.outu = outc;
    gemm_bt<128, 512><<<dim3(4, 35, 2), dim3(512), 0, stream>>>(wcfb, 4608, 0, pad + 128 * 512,
                                                                512, 4736L * 512, 4608, 1, 1, e);
  }
}